// Round 8
// baseline (93.220 us; speedup 1.0000x reference)
//
#include <hip/hip_runtime.h>
#include <math.h>

#define N_NODES 8192
#define KNN 9

// Fully-unrolled, statically-indexed carry-bubble insert into sorted-ascending
// top-9 (strict <, so equal keys keep the incumbent = lower index first; feed
// candidates in ascending index order to match jax.lax.top_k stability).
__device__ __forceinline__ void insert9(float (&td)[9], int (&ti)[9], float d, int idx) {
  float cd = d; int ci = idx;
#pragma unroll
  for (int k = 0; k < 9; ++k) {
    bool c = cd < td[k];
    float od = td[k]; int oi = ti[k];
    td[k] = c ? cd : od;  ti[k] = c ? ci : oi;
    cd = c ? od : cd;     ci = c ? oi : ci;
  }
}

// K1: x[B,C,H,W] -> xf[N,C] via LDS tile transpose (coalesced both ways);
// sq[n] = ||xf[n]||^2 ; zero deg.
__global__ __launch_bounds__(256) void k_prep(const float* __restrict__ x,
                                              float* __restrict__ xf,
                                              float* __restrict__ sq,
                                              int* __restrict__ deg) {
  __shared__ float t[64][65];
  const int b = blockIdx.x >> 4;
  const int hw0 = (blockIdx.x & 15) * 64;
  const int c0 = threadIdx.x >> 6;      // 0..3
  const int hwl = threadIdx.x & 63;
#pragma unroll
  for (int i = 0; i < 16; ++i) {
    int c = i * 4 + c0;
    t[c][hwl] = x[((size_t)(b * 64 + c)) * 1024 + hw0 + hwl];
  }
  __syncthreads();
  const int wave = threadIdx.x >> 6;    // 0..3
  const int lane = threadIdx.x & 63;    // channel
#pragma unroll
  for (int i = 0; i < 16; ++i) {
    int r = i * 4 + wave;               // hw row within tile
    float v = t[lane][r];
    int n = b * 1024 + hw0 + r;
    xf[(size_t)n * 64 + lane] = v;      // lanes along c -> 256B contiguous
    float s = v * v;
#pragma unroll
    for (int m = 1; m < 64; m <<= 1) s += __shfl_xor(s, m);
    if (lane == 0) sq[n] = s;
  }
  int tid = blockIdx.x * 256 + threadIdx.x;
  if (tid < N_NODES) deg[tid] = 0;
}

// K2 (k_dist): pure distance GEMM. Block = 128 queries x 128 candidates,
// K = 64 channels, 256 threads, micro-tile 8q x 8c (acc[8][8]).
// Q staged once in LDS (32KB, 2 b128 reads/k/thread -> LDS pipe well under
// the FMA floor); C read straight from global x (channel-major already):
// per k one wave reads a 512B contiguous+broadcast slice -> L1/L2 resident.
// NO barriers after the Q-stage, no selection logic -> free-running FMA loop.
// d2 written to global ws buffer (row = query within pass, col = cand-bstart).
__global__ __launch_bounds__(256, 2) void k_dist(const float* __restrict__ x,
                                                 const float* __restrict__ sq,
                                                 float* __restrict__ d2g,
                                                 int qpass0) {
  __shared__ float Qs[64][128];
  const int t = threadIdx.x;
  const int q0 = qpass0 + blockIdx.x * 128;
  const int b = q0 >> 10;
  const int bstart = b << 10;
  const int ct = blockIdx.y;                 // 0..7
  const int cbase = bstart + ct * 128;
  const float4* xb4 = reinterpret_cast<const float4*>(x) + (size_t)b * 16384;

  // stage Q tile: Qs[k][ql] = x[b][k][(q0-bstart)+ql]  (coalesced)
  const int qoff4 = (q0 - bstart) >> 2;
#pragma unroll
  for (int i = 0; i < 8; ++i) {
    int idx = i * 256 + t;
    int k = idx >> 5, c4 = idx & 31;
    float4 v = xb4[(size_t)k * 256 + qoff4 + c4];
    *reinterpret_cast<float4*>(&Qs[k][c4 * 4]) = v;
  }
  __syncthreads();

  const int tq = t >> 4;    // 0..15 -> q rows tq*8..+7
  const int tc = t & 15;    // 0..15 -> c cols tc*8..+7

  float acc[8][8];
#pragma unroll
  for (int i = 0; i < 8; ++i)
#pragma unroll
    for (int j = 0; j < 8; ++j) acc[i][j] = 0.f;

  const float* cg = x + (size_t)b * 65536 + (size_t)(ct * 128 + tc * 8);
#pragma unroll 4
  for (int k = 0; k < 64; ++k) {
    float4 ca = *reinterpret_cast<const float4*>(cg + (size_t)k * 1024);
    float4 cb = *reinterpret_cast<const float4*>(cg + (size_t)k * 1024 + 4);
    float4 qa = *reinterpret_cast<const float4*>(&Qs[k][tq * 8]);
    float4 qb = *reinterpret_cast<const float4*>(&Qs[k][tq * 8 + 4]);
    float qv[8] = {qa.x, qa.y, qa.z, qa.w, qb.x, qb.y, qb.z, qb.w};
    float cv[8] = {ca.x, ca.y, ca.z, ca.w, cb.x, cb.y, cb.z, cb.w};
#pragma unroll
    for (int i = 0; i < 8; ++i)
#pragma unroll
      for (int j = 0; j < 8; ++j)
        acc[i][j] = fmaf(qv[i], cv[j], acc[i][j]);
  }

  // epilogue: d2 = (sqq + csq) - 2*dot   (same expression shape as before)
  float sqq[8], csq[8];
#pragma unroll
  for (int i = 0; i < 8; ++i) sqq[i] = sq[q0 + tq * 8 + i];
#pragma unroll
  for (int j = 0; j < 8; ++j) csq[j] = sq[cbase + tc * 8 + j];
#pragma unroll
  for (int i = 0; i < 8; ++i) {
    float* orow = d2g + (size_t)(q0 - qpass0 + tq * 8 + i) * 1024 + ct * 128 + tc * 8;
    float4 o1, o2;
    o1.x = fmaf(-2.f, acc[i][0], sqq[i] + csq[0]);
    o1.y = fmaf(-2.f, acc[i][1], sqq[i] + csq[1]);
    o1.z = fmaf(-2.f, acc[i][2], sqq[i] + csq[2]);
    o1.w = fmaf(-2.f, acc[i][3], sqq[i] + csq[3]);
    o2.x = fmaf(-2.f, acc[i][4], sqq[i] + csq[4]);
    o2.y = fmaf(-2.f, acc[i][5], sqq[i] + csq[5]);
    o2.z = fmaf(-2.f, acc[i][6], sqq[i] + csq[6]);
    o2.w = fmaf(-2.f, acc[i][7], sqq[i] + csq[7]);
    *reinterpret_cast<float4*>(orow) = o1;
    *reinterpret_cast<float4*>(orow + 4) = o2;
  }
}

// K3 (k_sel): selection + merge + degrees, fused. 16-lane group per query:
// lane s insert9-scans its contiguous 64-candidate slice (16 float4 loads),
// then 9 rounds of 16-lane argmin over u64 pack (orderedbits(d)<<32 | idx)
// = exact (d, idx)-lex order incl. possibly-negative self-distance; winner
// pops its sorted head. Writes idxf + deg directly (replaces old k_merge).
__device__ __forceinline__ unsigned long long packdi(float d, int idx) {
  unsigned int u = __float_as_uint(d);
  u = (u & 0x80000000u) ? ~u : (u | 0x80000000u);   // order-preserving map
  return ((unsigned long long)u << 32) | (unsigned int)idx;
}

__global__ __launch_bounds__(256) void k_sel(const float* __restrict__ d2g,
                                             int* __restrict__ idxf,
                                             int* __restrict__ deg,
                                             int qpass0) {
  const int t = threadIdx.x;
  const int s = t & 15;
  const int q = qpass0 + blockIdx.x * 16 + (t >> 4);

  if (q == N_NODES - 1) {
    // batch 8 = {8191}: self first, then -inf ties filled with indices 0..7
    if (s < KNN) {
      int nb = (s == 0) ? (N_NODES - 1) : (s - 1);
      idxf[q * KNN + s] = nb;
      if (nb != q) atomicAdd(&deg[nb], 1);
    }
    return;
  }

  const int bstart = (q >> 10) << 10;
  const int bend = min(bstart + 1024, N_NODES - 1);  // exclusive; drops 8191
  const int c0 = bstart + s * 64;
  const float4* row = reinterpret_cast<const float4*>(
      d2g + (size_t)(q - qpass0) * 1024 + s * 64);

  float td[9]; int ti[9];
#pragma unroll
  for (int k = 0; k < 9; ++k) { td[k] = 3.0e38f; ti[k] = 0x7fffffff; }

  for (int j4 = 0; j4 < 16; ++j4) {
    float4 v = row[j4];
    int cb = c0 + j4 * 4;
    if (v.x < td[8] && cb + 0 < bend) insert9(td, ti, v.x, cb + 0);
    if (v.y < td[8] && cb + 1 < bend) insert9(td, ti, v.y, cb + 1);
    if (v.z < td[8] && cb + 2 < bend) insert9(td, ti, v.z, cb + 2);
    if (v.w < td[8] && cb + 3 < bend) insert9(td, ti, v.w, cb + 3);
  }

  unsigned long long cur = packdi(td[0], ti[0]);
#pragma unroll
  for (int r = 0; r < KNN; ++r) {
    unsigned long long m = cur;
#pragma unroll
    for (int msk = 1; msk < 16; msk <<= 1) {
      unsigned long long o = __shfl_xor(m, msk);
      if (o < m) m = o;
    }
    if (s == r) {
      int bi = (int)(unsigned int)(m & 0xffffffffu);
      idxf[q * KNN + r] = bi;
      if (bi != q) atomicAdd(&deg[bi], 1);
    }
    if (cur == m) {                     // unique winner pops its head
#pragma unroll
      for (int k = 0; k < 8; ++k) { td[k] = td[k + 1]; ti[k] = ti[k + 1]; }
      td[8] = 3.2e38f; ti[8] = 0x7fffffff;
      cur = packdi(td[0], ti[0]);
    }
  }
}

// K4 (fused gather + output GEMM):
// phase 1: g[t] = sum_k (-dis[s_k] * dis[t]) * xf[s_k]  -> straight into LDS
// phase 2: out = xf @ W0 + g @ W1 + bias
__global__ __launch_bounds__(256) void k_gout(const float* __restrict__ xf,
                                              const int* __restrict__ idxf,
                                              const int* __restrict__ deg,
                                              const float* __restrict__ W0,
                                              const float* __restrict__ W1,
                                              const float* __restrict__ bias,
                                              float* __restrict__ out) {
  __shared__ float w0[64 * 64];
  __shared__ float w1[64 * 64];
  __shared__ float sx[16 * 65];   // +1 pad: kills 4-way bank conflict on row reads
  __shared__ float sg[16 * 65];
  const int nb = blockIdx.x * 16;

  float4* w04 = reinterpret_cast<float4*>(w0);
  float4* w14 = reinterpret_cast<float4*>(w1);
  const float4* W04 = reinterpret_cast<const float4*>(W0);
  const float4* W14 = reinterpret_cast<const float4*>(W1);
  for (int t = threadIdx.x; t < 1024; t += 256) { w04[t] = W04[t]; w14[t] = W14[t]; }
  for (int t = threadIdx.x; t < 1024; t += 256) {
    int ln = t >> 6, c = t & 63;
    sx[ln * 65 + c] = xf[(size_t)(nb + ln) * 64 + c];
  }
  {
    int ln = threadIdx.x >> 4, c4 = threadIdx.x & 15;
    int n = nb + ln;
    int dt = deg[n];
    float dis_t = dt > 0 ? 1.f / sqrtf((float)dt) : 0.f;
    float ax = 0.f, ay = 0.f, az = 0.f, aw = 0.f;
#pragma unroll
    for (int k = 0; k < 9; ++k) {
      int s = idxf[n * KNN + k];
      if (s == n) continue;                    // self loop: w=0 -> norm 0
      int ds = deg[s];
      float dis_s = ds > 0 ? 1.f / sqrtf((float)ds) : 0.f;
      float w = -dis_s * dis_t;
      float4 v = reinterpret_cast<const float4*>(xf + (size_t)s * 64)[c4];
      ax = fmaf(w, v.x, ax); ay = fmaf(w, v.y, ay);
      az = fmaf(w, v.z, az); aw = fmaf(w, v.w, aw);
    }
    sg[ln * 65 + c4 * 4 + 0] = ax;
    sg[ln * 65 + c4 * 4 + 1] = ay;
    sg[ln * 65 + c4 * 4 + 2] = az;
    sg[ln * 65 + c4 * 4 + 3] = aw;
  }
  __syncthreads();
  int ln = threadIdx.x >> 4, o4 = threadIdx.x & 15;
  float4 acc = reinterpret_cast<const float4*>(bias)[o4];
#pragma unroll
  for (int c = 0; c < 64; ++c) {
    float xv = sx[ln * 65 + c];
    float gv = sg[ln * 65 + c];
    float4 v0 = reinterpret_cast<const float4*>(w0 + c * 64)[o4];
    float4 v1 = reinterpret_cast<const float4*>(w1 + c * 64)[o4];
    acc.x = fmaf(xv, v0.x, acc.x); acc.y = fmaf(xv, v0.y, acc.y);
    acc.z = fmaf(xv, v0.z, acc.z); acc.w = fmaf(xv, v0.w, acc.w);
    acc.x = fmaf(gv, v1.x, acc.x); acc.y = fmaf(gv, v1.y, acc.y);
    acc.z = fmaf(gv, v1.z, acc.z); acc.w = fmaf(gv, v1.w, acc.w);
  }
  reinterpret_cast<float4*>(out)[(size_t)(nb + ln) * 16 + o4] = acc;
}

extern "C" void kernel_launch(void* const* d_in, const int* in_sizes, int n_in,
                              void* d_out, int out_size, void* d_ws, size_t ws_size,
                              hipStream_t stream) {
  const float* x    = (const float*)d_in[0];
  const float* W0   = (const float*)d_in[1];
  const float* W1   = (const float*)d_in[2];
  const float* bias = (const float*)d_in[3];
  float* out = (float*)d_out;
  char* ws = (char*)d_ws;

  // workspace layout
  float* xf   = (float*)(ws);                       // 8192*64*4 = 2,097,152
  float* sq   = (float*)(ws + 2097152);             // 32,768
  int*   deg  = (int*)  (ws + 2129920);             // 32,768
  int*   idxf = (int*)  (ws + 2162688);             // 8192*9*4 = 294,912
  float* d2g  = (float*)(ws + 2457600);             // d2 panel (per pass)

  // passes: reuse d2g across query ranges if ws is too small for 33.5MB
  int passes = 1;
  while (passes < 8) {
    size_t need = 2457600 + ((size_t)N_NODES / passes) * 1024 * 4;
    if (need <= ws_size) break;
    passes <<= 1;
  }
  const int QH = N_NODES / passes;

  k_prep<<<128, 256, 0, stream>>>(x, xf, sq, deg);
  for (int p = 0; p < passes; ++p) {
    const int q00 = p * QH;
    k_dist<<<dim3(QH / 128, 8), 256, 0, stream>>>(x, sq, d2g, q00);
    k_sel <<<QH / 16, 256, 0, stream>>>(d2g, idxf, deg, q00);
  }
  k_gout<<<512, 256, 0, stream>>>(xf, idxf, deg, W0, W1, bias, out);
}

// Round 9
// 76.707 us; speedup vs baseline: 1.2153x; 1.2153x over previous
//
#include <hip/hip_runtime.h>
#include <math.h>

#define N_NODES 8192
#define KNN 9

// Fully-unrolled, statically-indexed carry-bubble insert into sorted-ascending
// top-9 (strict <; feed candidates in ascending index order per lane).
__device__ __forceinline__ void insert9(float (&td)[9], int (&ti)[9], float d, int idx) {
  float cd = d; int ci = idx;
#pragma unroll
  for (int k = 0; k < 9; ++k) {
    bool c = cd < td[k];
    float od = td[k]; int oi = ti[k];
    td[k] = c ? cd : od;  ti[k] = c ? ci : oi;
    cd = c ? od : cd;     ci = c ? oi : ci;
  }
}

// order-preserving float->uint map packed with index: exact (d, idx) lex order
__device__ __forceinline__ unsigned long long packdi(float d, int idx) {
  unsigned int u = __float_as_uint(d);
  u = (u & 0x80000000u) ? ~u : (u | 0x80000000u);
  return ((unsigned long long)u << 32) | (unsigned int)idx;
}

// K1: x[B,C,H,W] -> xf[N,C] via LDS tile transpose (coalesced both ways);
// sq[n] = ||xf[n]||^2 ; zero deg.
__global__ __launch_bounds__(256) void k_prep(const float* __restrict__ x,
                                              float* __restrict__ xf,
                                              float* __restrict__ sq,
                                              int* __restrict__ deg) {
  __shared__ float t[64][65];
  const int b = blockIdx.x >> 4;
  const int hw0 = (blockIdx.x & 15) * 64;
  const int c0 = threadIdx.x >> 6;      // 0..3
  const int hwl = threadIdx.x & 63;
#pragma unroll
  for (int i = 0; i < 16; ++i) {
    int c = i * 4 + c0;
    t[c][hwl] = x[((size_t)(b * 64 + c)) * 1024 + hw0 + hwl];
  }
  __syncthreads();
  const int wave = threadIdx.x >> 6;    // 0..3
  const int lane = threadIdx.x & 63;    // channel
#pragma unroll
  for (int i = 0; i < 16; ++i) {
    int r = i * 4 + wave;               // hw row within tile
    float v = t[lane][r];
    int n = b * 1024 + hw0 + r;
    xf[(size_t)n * 64 + lane] = v;      // lanes along c -> 256B contiguous
    float s = v * v;
#pragma unroll
    for (int m = 1; m < 64; m <<= 1) s += __shfl_xor(s, m);
    if (lane == 0) sq[n] = s;
  }
  int tid = blockIdx.x * 256 + threadIdx.x;
  if (tid < N_NODES) deg[tid] = 0;
}

// K2 (k_dist): pure distance GEMM. Block = 128 queries x 128 candidates,
// K=64, 256 threads, micro-tile 8q x 8c. Q staged once in LDS; C pair
// register-prefetched one k ahead (round-8 version had the raw L2-latency
// load chained into the FMA block). No barriers after Q-stage.
__global__ __launch_bounds__(256, 4) void k_dist(const float* __restrict__ x,
                                                 const float* __restrict__ sq,
                                                 float* __restrict__ d2g,
                                                 int qpass0) {
  __shared__ float Qs[64][128];
  const int t = threadIdx.x;
  const int q0 = qpass0 + blockIdx.x * 128;
  const int b = q0 >> 10;
  const int bstart = b << 10;
  const int ct = blockIdx.y;                 // 0..7
  const int cbase = bstart + ct * 128;
  const float4* xb4 = reinterpret_cast<const float4*>(x) + (size_t)b * 16384;

  const int qoff4 = (q0 - bstart) >> 2;
#pragma unroll
  for (int i = 0; i < 8; ++i) {
    int idx = i * 256 + t;
    int k = idx >> 5, c4 = idx & 31;
    float4 v = xb4[(size_t)k * 256 + qoff4 + c4];
    *reinterpret_cast<float4*>(&Qs[k][c4 * 4]) = v;
  }
  __syncthreads();

  const int tq = t >> 4;    // 0..15 -> q rows tq*8..+7
  const int tc = t & 15;    // 0..15 -> c cols tc*8..+7

  float acc[8][8];
#pragma unroll
  for (int i = 0; i < 8; ++i)
#pragma unroll
    for (int j = 0; j < 8; ++j) acc[i][j] = 0.f;

  const float* cg = x + (size_t)b * 65536 + (size_t)(ct * 128 + tc * 8);
  float4 ca = *reinterpret_cast<const float4*>(cg);
  float4 cb = *reinterpret_cast<const float4*>(cg + 4);
#pragma unroll 4
  for (int k = 0; k < 64; ++k) {
    float4 na, nb;
    if (k < 63) {
      na = *reinterpret_cast<const float4*>(cg + (size_t)(k + 1) * 1024);
      nb = *reinterpret_cast<const float4*>(cg + (size_t)(k + 1) * 1024 + 4);
    }
    float4 qa = *reinterpret_cast<const float4*>(&Qs[k][tq * 8]);
    float4 qb = *reinterpret_cast<const float4*>(&Qs[k][tq * 8 + 4]);
    float qv[8] = {qa.x, qa.y, qa.z, qa.w, qb.x, qb.y, qb.z, qb.w};
    float cv[8] = {ca.x, ca.y, ca.z, ca.w, cb.x, cb.y, cb.z, cb.w};
#pragma unroll
    for (int i = 0; i < 8; ++i)
#pragma unroll
      for (int j = 0; j < 8; ++j)
        acc[i][j] = fmaf(qv[i], cv[j], acc[i][j]);
    ca = na; cb = nb;
  }

  float sqq[8], csq[8];
#pragma unroll
  for (int i = 0; i < 8; ++i) sqq[i] = sq[q0 + tq * 8 + i];
#pragma unroll
  for (int j = 0; j < 8; ++j) csq[j] = sq[cbase + tc * 8 + j];
#pragma unroll
  for (int i = 0; i < 8; ++i) {
    float* orow = d2g + (size_t)(q0 - qpass0 + tq * 8 + i) * 1024 + ct * 128 + tc * 8;
    float4 o1, o2;
    o1.x = fmaf(-2.f, acc[i][0], sqq[i] + csq[0]);
    o1.y = fmaf(-2.f, acc[i][1], sqq[i] + csq[1]);
    o1.z = fmaf(-2.f, acc[i][2], sqq[i] + csq[2]);
    o1.w = fmaf(-2.f, acc[i][3], sqq[i] + csq[3]);
    o2.x = fmaf(-2.f, acc[i][4], sqq[i] + csq[4]);
    o2.y = fmaf(-2.f, acc[i][5], sqq[i] + csq[5]);
    o2.z = fmaf(-2.f, acc[i][6], sqq[i] + csq[6]);
    o2.w = fmaf(-2.f, acc[i][7], sqq[i] + csq[7]);
    *reinterpret_cast<float4*>(orow) = o1;
    *reinterpret_cast<float4*>(orow + 4) = o2;
  }
}

// K3 (k_sel): one WAVE per query (fully coalesced: per load-instr the wave
// reads 1KB contiguous of the query's d2 row). Lane l sees candidates
// {256*i + 4l + j} (ascending per lane), keeps a private sorted top-9, then
// 9 rounds of 64-lane u64-pack argmin = exact (d, idx)-lex top_k semantics.
// Writes idxf + deg directly.
__global__ __launch_bounds__(256) void k_sel(const float* __restrict__ d2g,
                                             int* __restrict__ idxf,
                                             int* __restrict__ deg,
                                             int qpass0) {
  const int lane = threadIdx.x & 63;
  const int q = qpass0 + blockIdx.x * 4 + (threadIdx.x >> 6);

  if (q == N_NODES - 1) {
    // batch 8 = {8191}: self first, then -inf ties filled with indices 0..7
    if (lane < KNN) {
      int nb = (lane == 0) ? (N_NODES - 1) : (lane - 1);
      idxf[q * KNN + lane] = nb;
      if (nb != q) atomicAdd(&deg[nb], 1);
    }
    return;
  }

  const int bstart = (q >> 10) << 10;
  const int lim = (bstart == 7168) ? 1023 : 1024;   // exclude node 8191
  const float4* row = reinterpret_cast<const float4*>(d2g + (size_t)(q - qpass0) * 1024);

  float td[9]; int ti[9];
#pragma unroll
  for (int k = 0; k < 9; ++k) { td[k] = 3.0e38f; ti[k] = 0x7fffffff; }

#pragma unroll
  for (int i = 0; i < 4; ++i) {
    float4 v = row[i * 64 + lane];
    int c = i * 256 + lane * 4;
    if (v.x < td[8] && c + 0 < lim) insert9(td, ti, v.x, bstart + c + 0);
    if (v.y < td[8] && c + 1 < lim) insert9(td, ti, v.y, bstart + c + 1);
    if (v.z < td[8] && c + 2 < lim) insert9(td, ti, v.z, bstart + c + 2);
    if (v.w < td[8] && c + 3 < lim) insert9(td, ti, v.w, bstart + c + 3);
  }

  unsigned long long cur = packdi(td[0], ti[0]);
#pragma unroll
  for (int r = 0; r < KNN; ++r) {
    unsigned long long m = cur;
#pragma unroll
    for (int msk = 1; msk < 64; msk <<= 1) {
      unsigned long long o = __shfl_xor(m, msk);
      if (o < m) m = o;
    }
    if (lane == r) {
      int bi = (int)(unsigned int)(m & 0xffffffffu);
      idxf[q * KNN + r] = bi;
      if (bi != q) atomicAdd(&deg[bi], 1);
    }
    if (cur == m) {                     // unique winner pops its sorted head
#pragma unroll
      for (int k = 0; k < 8; ++k) { td[k] = td[k + 1]; ti[k] = ti[k + 1]; }
      td[8] = 3.2e38f; ti[8] = 0x7fffffff;
      cur = packdi(td[0], ti[0]);
    }
  }
}

// K4 (fused gather + output GEMM), 32 nodes/block, 2 rows/thread:
// weight LDS reads amortized over 2 rows (v0/v1 loaded once per c), weight
// global traffic halved vs 16-node blocks.
__global__ __launch_bounds__(256) void k_gout(const float* __restrict__ xf,
                                              const int* __restrict__ idxf,
                                              const int* __restrict__ deg,
                                              const float* __restrict__ W0,
                                              const float* __restrict__ W1,
                                              const float* __restrict__ bias,
                                              float* __restrict__ out) {
  __shared__ float w0[64 * 64];
  __shared__ float w1[64 * 64];
  __shared__ float sx[32 * 65];
  __shared__ float sg[32 * 65];
  const int nb = blockIdx.x * 32;
  const int t = threadIdx.x;

  float4* w04 = reinterpret_cast<float4*>(w0);
  float4* w14 = reinterpret_cast<float4*>(w1);
  const float4* W04 = reinterpret_cast<const float4*>(W0);
  const float4* W14 = reinterpret_cast<const float4*>(W1);
  for (int i = t; i < 1024; i += 256) { w04[i] = W04[i]; w14[i] = W14[i]; }
  for (int i = t; i < 2048; i += 256) {
    int ln = i >> 6, c = i & 63;
    sx[ln * 65 + c] = xf[(size_t)(nb + ln) * 64 + c];
  }
  // gather phase: 2 items/thread, item = (node ln, channel-quad c4)
#pragma unroll
  for (int it = 0; it < 2; ++it) {
    int item = it * 256 + t;
    int ln = item >> 4, c4 = item & 15;
    int n = nb + ln;
    int dt = deg[n];
    float dis_t = dt > 0 ? 1.f / sqrtf((float)dt) : 0.f;
    float ax = 0.f, ay = 0.f, az = 0.f, aw = 0.f;
#pragma unroll
    for (int k = 0; k < 9; ++k) {
      int s = idxf[n * KNN + k];
      if (s == n) continue;                    // self loop: w=0 -> norm 0
      int ds = deg[s];
      float dis_s = ds > 0 ? 1.f / sqrtf((float)ds) : 0.f;
      float w = -dis_s * dis_t;
      float4 v = reinterpret_cast<const float4*>(xf + (size_t)s * 64)[c4];
      ax = fmaf(w, v.x, ax); ay = fmaf(w, v.y, ay);
      az = fmaf(w, v.z, az); aw = fmaf(w, v.w, aw);
    }
    sg[ln * 65 + c4 * 4 + 0] = ax;
    sg[ln * 65 + c4 * 4 + 1] = ay;
    sg[ln * 65 + c4 * 4 + 2] = az;
    sg[ln * 65 + c4 * 4 + 3] = aw;
  }
  __syncthreads();

  const int ln2 = t >> 4, o4 = t & 15;
  float4 bv = reinterpret_cast<const float4*>(bias)[o4];
  float4 a0 = bv, a1 = bv;
#pragma unroll
  for (int c = 0; c < 64; ++c) {
    float4 v0 = reinterpret_cast<const float4*>(w0 + c * 64)[o4];
    float4 v1 = reinterpret_cast<const float4*>(w1 + c * 64)[o4];
    float xv0 = sx[ln2 * 65 + c],        gv0 = sg[ln2 * 65 + c];
    float xv1 = sx[(ln2 + 16) * 65 + c], gv1 = sg[(ln2 + 16) * 65 + c];
    a0.x = fmaf(xv0, v0.x, a0.x); a0.y = fmaf(xv0, v0.y, a0.y);
    a0.z = fmaf(xv0, v0.z, a0.z); a0.w = fmaf(xv0, v0.w, a0.w);
    a0.x = fmaf(gv0, v1.x, a0.x); a0.y = fmaf(gv0, v1.y, a0.y);
    a0.z = fmaf(gv0, v1.z, a0.z); a0.w = fmaf(gv0, v1.w, a0.w);
    a1.x = fmaf(xv1, v0.x, a1.x); a1.y = fmaf(xv1, v0.y, a1.y);
    a1.z = fmaf(xv1, v0.z, a1.z); a1.w = fmaf(xv1, v0.w, a1.w);
    a1.x = fmaf(gv1, v1.x, a1.x); a1.y = fmaf(gv1, v1.y, a1.y);
    a1.z = fmaf(gv1, v1.z, a1.z); a1.w = fmaf(gv1, v1.w, a1.w);
  }
  reinterpret_cast<float4*>(out)[(size_t)(nb + ln2) * 16 + o4] = a0;
  reinterpret_cast<float4*>(out)[(size_t)(nb + ln2 + 16) * 16 + o4] = a1;
}

extern "C" void kernel_launch(void* const* d_in, const int* in_sizes, int n_in,
                              void* d_out, int out_size, void* d_ws, size_t ws_size,
                              hipStream_t stream) {
  const float* x    = (const float*)d_in[0];
  const float* W0   = (const float*)d_in[1];
  const float* W1   = (const float*)d_in[2];
  const float* bias = (const float*)d_in[3];
  float* out = (float*)d_out;
  char* ws = (char*)d_ws;

  // workspace layout
  float* xf   = (float*)(ws);                       // 8192*64*4 = 2,097,152
  float* sq   = (float*)(ws + 2097152);             // 32,768
  int*   deg  = (int*)  (ws + 2129920);             // 32,768
  int*   idxf = (int*)  (ws + 2162688);             // 8192*9*4 = 294,912
  float* d2g  = (float*)(ws + 2457600);             // d2 panel (per pass)

  // passes: reuse d2g across query ranges if ws too small for 33.5MB
  // (observed ws_size ~268MB -> passes = 1)
  int passes = 1;
  while (passes < 8) {
    size_t need = 2457600 + ((size_t)N_NODES / passes) * 1024 * 4;
    if (need <= ws_size) break;
    passes <<= 1;
  }
  const int QH = N_NODES / passes;

  k_prep<<<128, 256, 0, stream>>>(x, xf, sq, deg);
  for (int p = 0; p < passes; ++p) {
    const int q00 = p * QH;
    k_dist<<<dim3(QH / 128, 8), 256, 0, stream>>>(x, sq, d2g, q00);
    k_sel <<<QH / 4, 256, 0, stream>>>(d2g, idxf, deg, q00);
  }
  k_gout<<<256, 256, 0, stream>>>(xf, idxf, deg, W0, W1, bias, out);
}

// Round 10
// 65.546 us; speedup vs baseline: 1.4222x; 1.1703x over previous
//
#include <hip/hip_runtime.h>
#include <math.h>

#define N_NODES 8192
#define KNN 9

// order-preserving float->uint map packed with index: exact (d, idx) lex order
__device__ __forceinline__ unsigned long long packdi(float d, int idx) {
  unsigned int u = __float_as_uint(d);
  u = (u & 0x80000000u) ? ~u : (u | 0x80000000u);
  return ((unsigned long long)u << 32) | (unsigned int)idx;
}

// K1: x[B,C,H,W] -> xf[N,C] via LDS tile transpose (coalesced both ways);
// sq[n] = ||xf[n]||^2 ; zero deg.
__global__ __launch_bounds__(256) void k_prep(const float* __restrict__ x,
                                              float* __restrict__ xf,
                                              float* __restrict__ sq,
                                              int* __restrict__ deg) {
  __shared__ float t[64][65];
  const int b = blockIdx.x >> 4;
  const int hw0 = (blockIdx.x & 15) * 64;
  const int c0 = threadIdx.x >> 6;      // 0..3
  const int hwl = threadIdx.x & 63;
#pragma unroll
  for (int i = 0; i < 16; ++i) {
    int c = i * 4 + c0;
    t[c][hwl] = x[((size_t)(b * 64 + c)) * 1024 + hw0 + hwl];
  }
  __syncthreads();
  const int wave = threadIdx.x >> 6;    // 0..3
  const int lane = threadIdx.x & 63;    // channel
#pragma unroll
  for (int i = 0; i < 16; ++i) {
    int r = i * 4 + wave;               // hw row within tile
    float v = t[lane][r];
    int n = b * 1024 + hw0 + r;
    xf[(size_t)n * 64 + lane] = v;      // lanes along c -> 256B contiguous
    float s = v * v;
#pragma unroll
    for (int m = 1; m < 64; m <<= 1) s += __shfl_xor(s, m);
    if (lane == 0) sq[n] = s;
  }
  int tid = blockIdx.x * 256 + threadIdx.x;
  if (tid < N_NODES) deg[tid] = 0;
}

// K2 (k_dist): pure distance GEMM. Block = 128 queries x 128 candidates,
// K=64, 256 threads, micro-tile 8q x 8c. Q staged once in LDS; C pair
// register-prefetched one k ahead. No barriers after Q-stage.
__global__ __launch_bounds__(256, 4) void k_dist(const float* __restrict__ x,
                                                 const float* __restrict__ sq,
                                                 float* __restrict__ d2g,
                                                 int qpass0) {
  __shared__ float Qs[64][128];
  const int t = threadIdx.x;
  const int q0 = qpass0 + blockIdx.x * 128;
  const int b = q0 >> 10;
  const int bstart = b << 10;
  const int ct = blockIdx.y;                 // 0..7
  const int cbase = bstart + ct * 128;
  const float4* xb4 = reinterpret_cast<const float4*>(x) + (size_t)b * 16384;

  const int qoff4 = (q0 - bstart) >> 2;
#pragma unroll
  for (int i = 0; i < 8; ++i) {
    int idx = i * 256 + t;
    int k = idx >> 5, c4 = idx & 31;
    float4 v = xb4[(size_t)k * 256 + qoff4 + c4];
    *reinterpret_cast<float4*>(&Qs[k][c4 * 4]) = v;
  }
  __syncthreads();

  const int tq = t >> 4;    // 0..15 -> q rows tq*8..+7
  const int tc = t & 15;    // 0..15 -> c cols tc*8..+7

  float acc[8][8];
#pragma unroll
  for (int i = 0; i < 8; ++i)
#pragma unroll
    for (int j = 0; j < 8; ++j) acc[i][j] = 0.f;

  const float* cg = x + (size_t)b * 65536 + (size_t)(ct * 128 + tc * 8);
  float4 ca = *reinterpret_cast<const float4*>(cg);
  float4 cb = *reinterpret_cast<const float4*>(cg + 4);
#pragma unroll 4
  for (int k = 0; k < 64; ++k) {
    float4 na, nb;
    if (k < 63) {
      na = *reinterpret_cast<const float4*>(cg + (size_t)(k + 1) * 1024);
      nb = *reinterpret_cast<const float4*>(cg + (size_t)(k + 1) * 1024 + 4);
    }
    float4 qa = *reinterpret_cast<const float4*>(&Qs[k][tq * 8]);
    float4 qb = *reinterpret_cast<const float4*>(&Qs[k][tq * 8 + 4]);
    float qv[8] = {qa.x, qa.y, qa.z, qa.w, qb.x, qb.y, qb.z, qb.w};
    float cv[8] = {ca.x, ca.y, ca.z, ca.w, cb.x, cb.y, cb.z, cb.w};
#pragma unroll
    for (int i = 0; i < 8; ++i)
#pragma unroll
      for (int j = 0; j < 8; ++j)
        acc[i][j] = fmaf(qv[i], cv[j], acc[i][j]);
    ca = na; cb = nb;
  }

  float sqq[8], csq[8];
#pragma unroll
  for (int i = 0; i < 8; ++i) sqq[i] = sq[q0 + tq * 8 + i];
#pragma unroll
  for (int j = 0; j < 8; ++j) csq[j] = sq[cbase + tc * 8 + j];
#pragma unroll
  for (int i = 0; i < 8; ++i) {
    float* orow = d2g + (size_t)(q0 - qpass0 + tq * 8 + i) * 1024 + ct * 128 + tc * 8;
    float4 o1, o2;
    o1.x = fmaf(-2.f, acc[i][0], sqq[i] + csq[0]);
    o1.y = fmaf(-2.f, acc[i][1], sqq[i] + csq[1]);
    o1.z = fmaf(-2.f, acc[i][2], sqq[i] + csq[2]);
    o1.w = fmaf(-2.f, acc[i][3], sqq[i] + csq[3]);
    o2.x = fmaf(-2.f, acc[i][4], sqq[i] + csq[4]);
    o2.y = fmaf(-2.f, acc[i][5], sqq[i] + csq[5]);
    o2.z = fmaf(-2.f, acc[i][6], sqq[i] + csq[6]);
    o2.w = fmaf(-2.f, acc[i][7], sqq[i] + csq[7]);
    *reinterpret_cast<float4*>(orow) = o1;
    *reinterpret_cast<float4*>(orow + 4) = o2;
  }
}

// K3 (k_sel): one WAVE per query, branch-free selection.
// Lane packs its 16 coalesced values into u64 (orderedbits(d)::idx), sorts
// them with a 63-CE Batcher odd-even network (static indices, no divergence),
// then 9 rounds of 64-lane u64 argmin + pop-shift emit the exact (d,idx)-lex
// top-9 in order. Replaces the wave-divergence-amplified insert9 scan
// (~64 any-lane inserts x 45 ops) with ~930 uniform VALU ops.
__global__ __launch_bounds__(256) void k_sel(const float* __restrict__ d2g,
                                             int* __restrict__ idxf,
                                             int* __restrict__ deg,
                                             int qpass0) {
  const int lane = threadIdx.x & 63;
  const int q = qpass0 + blockIdx.x * 4 + (threadIdx.x >> 6);

  if (q == N_NODES - 1) {
    // batch 8 = {8191}: self first, then -inf ties filled with indices 0..7
    if (lane < KNN) {
      int nb = (lane == 0) ? (N_NODES - 1) : (lane - 1);
      idxf[q * KNN + lane] = nb;
      if (nb != q) atomicAdd(&deg[nb], 1);
    }
    return;
  }

  const int bstart = (q >> 10) << 10;
  const int lim = (bstart == 7168) ? 1023 : 1024;   // exclude node 8191
  const float4* row = reinterpret_cast<const float4*>(d2g + (size_t)(q - qpass0) * 1024);

  unsigned long long p[16];
#pragma unroll
  for (int i = 0; i < 4; ++i) {
    float4 v = row[i * 64 + lane];
    int c = i * 256 + lane * 4;
    p[4 * i + 0] = (c + 0 < lim) ? packdi(v.x, bstart + c + 0) : ~0ULL;
    p[4 * i + 1] = (c + 1 < lim) ? packdi(v.y, bstart + c + 1) : ~0ULL;
    p[4 * i + 2] = (c + 2 < lim) ? packdi(v.z, bstart + c + 2) : ~0ULL;
    p[4 * i + 3] = (c + 3 < lim) ? packdi(v.w, bstart + c + 3) : ~0ULL;
  }

  // Batcher odd-even merge sort, n=16, 63 compare-exchanges (ascending)
#define CE(a, b) { unsigned long long ta = p[a], tb = p[b]; bool sw = tb < ta; \
                   p[a] = sw ? tb : ta; p[b] = sw ? ta : tb; }
  CE(0,1) CE(2,3) CE(4,5) CE(6,7) CE(8,9) CE(10,11) CE(12,13) CE(14,15)
  CE(0,2) CE(1,3) CE(1,2)  CE(4,6) CE(5,7) CE(5,6)
  CE(8,10) CE(9,11) CE(9,10)  CE(12,14) CE(13,15) CE(13,14)
  CE(0,4) CE(1,5) CE(2,6) CE(3,7) CE(2,4) CE(3,5) CE(1,2) CE(3,4) CE(5,6)
  CE(8,12) CE(9,13) CE(10,14) CE(11,15) CE(10,12) CE(11,13) CE(9,10) CE(11,12) CE(13,14)
  CE(0,8) CE(1,9) CE(2,10) CE(3,11) CE(4,12) CE(5,13) CE(6,14) CE(7,15)
  CE(4,8) CE(5,9) CE(6,10) CE(7,11)
  CE(2,4) CE(3,5) CE(6,8) CE(7,9) CE(10,12) CE(11,13)
  CE(1,2) CE(3,4) CE(5,6) CE(7,8) CE(9,10) CE(11,12) CE(13,14)
#undef CE

  unsigned long long cur = p[0];
#pragma unroll
  for (int r = 0; r < KNN; ++r) {
    unsigned long long m = cur;
#pragma unroll
    for (int msk = 1; msk < 64; msk <<= 1) {
      unsigned long long o = __shfl_xor(m, msk);
      if (o < m) m = o;
    }
    if (lane == r) {
      int bi = (int)(unsigned int)(m & 0xffffffffu);
      idxf[q * KNN + r] = bi;
      if (bi != q) atomicAdd(&deg[bi], 1);
    }
    if (cur == m) {                     // unique winner pops its sorted head
      p[0] = p[1]; p[1] = p[2]; p[2] = p[3]; p[3] = p[4];
      p[4] = p[5]; p[5] = p[6]; p[6] = p[7]; p[7] = p[8];
      p[8] = ~0ULL;
      cur = p[0];
    }
  }
}

// K4 (fused gather + output GEMM), 16 nodes/block, grid 512 -> 2 blocks/CU
// (round-9 ran 1 block/CU = 1 wave/SIMD; the scattered gather loads had no
// TLP to hide their L2 latency). sx/sg stride 68 = 16B-aligned float4 rows.
__global__ __launch_bounds__(256) void k_gout(const float* __restrict__ xf,
                                              const int* __restrict__ idxf,
                                              const int* __restrict__ deg,
                                              const float* __restrict__ W0,
                                              const float* __restrict__ W1,
                                              const float* __restrict__ bias,
                                              float* __restrict__ out) {
  __shared__ float w0[64 * 64];
  __shared__ float w1[64 * 64];
  __shared__ float sx[16 * 68];
  __shared__ float sg[16 * 68];
  const int nb = blockIdx.x * 16;
  const int t = threadIdx.x;

  float4* w04 = reinterpret_cast<float4*>(w0);
  float4* w14 = reinterpret_cast<float4*>(w1);
  const float4* W04 = reinterpret_cast<const float4*>(W0);
  const float4* W14 = reinterpret_cast<const float4*>(W1);
#pragma unroll
  for (int i = 0; i < 4; ++i) { w04[i * 256 + t] = W04[i * 256 + t]; w14[i * 256 + t] = W14[i * 256 + t]; }
  {
    int ln = t >> 4, c4 = t & 15;
    float4 v = reinterpret_cast<const float4*>(xf + (size_t)(nb + ln) * 64)[c4];
    *reinterpret_cast<float4*>(&sx[ln * 68 + c4 * 4]) = v;
  }
  // gather phase: 1 item/thread, item = (node ln, channel-quad c4)
  {
    int ln = t >> 4, c4 = t & 15;
    int n = nb + ln;
    int dt = deg[n];
    float dis_t = dt > 0 ? 1.f / sqrtf((float)dt) : 0.f;
    float ax = 0.f, ay = 0.f, az = 0.f, aw = 0.f;
#pragma unroll
    for (int k = 0; k < 9; ++k) {
      int s = idxf[n * KNN + k];
      if (s == n) continue;                    // self loop: w=0 -> norm 0
      int ds = deg[s];
      float dis_s = ds > 0 ? 1.f / sqrtf((float)ds) : 0.f;
      float w = -dis_s * dis_t;
      float4 v = reinterpret_cast<const float4*>(xf + (size_t)s * 64)[c4];
      ax = fmaf(w, v.x, ax); ay = fmaf(w, v.y, ay);
      az = fmaf(w, v.z, az); aw = fmaf(w, v.w, aw);
    }
    float4 r; r.x = ax; r.y = ay; r.z = az; r.w = aw;
    *reinterpret_cast<float4*>(&sg[ln * 68 + c4 * 4]) = r;
  }
  __syncthreads();

  const int ln2 = t >> 4, o4 = t & 15;
  float4 a0 = reinterpret_cast<const float4*>(bias)[o4];
#pragma unroll
  for (int c = 0; c < 64; ++c) {
    float4 v0 = reinterpret_cast<const float4*>(w0 + c * 64)[o4];
    float4 v1 = reinterpret_cast<const float4*>(w1 + c * 64)[o4];
    float xv = sx[ln2 * 68 + c];
    float gv = sg[ln2 * 68 + c];
    a0.x = fmaf(xv, v0.x, a0.x); a0.y = fmaf(xv, v0.y, a0.y);
    a0.z = fmaf(xv, v0.z, a0.z); a0.w = fmaf(xv, v0.w, a0.w);
    a0.x = fmaf(gv, v1.x, a0.x); a0.y = fmaf(gv, v1.y, a0.y);
    a0.z = fmaf(gv, v1.z, a0.z); a0.w = fmaf(gv, v1.w, a0.w);
  }
  reinterpret_cast<float4*>(out)[(size_t)(nb + ln2) * 16 + o4] = a0;
}

extern "C" void kernel_launch(void* const* d_in, const int* in_sizes, int n_in,
                              void* d_out, int out_size, void* d_ws, size_t ws_size,
                              hipStream_t stream) {
  const float* x    = (const float*)d_in[0];
  const float* W0   = (const float*)d_in[1];
  const float* W1   = (const float*)d_in[2];
  const float* bias = (const float*)d_in[3];
  float* out = (float*)d_out;
  char* ws = (char*)d_ws;

  // workspace layout
  float* xf   = (float*)(ws);                       // 8192*64*4 = 2,097,152
  float* sq   = (float*)(ws + 2097152);             // 32,768
  int*   deg  = (int*)  (ws + 2129920);             // 32,768
  int*   idxf = (int*)  (ws + 2162688);             // 8192*9*4 = 294,912
  float* d2g  = (float*)(ws + 2457600);             // d2 panel (per pass)

  // passes: reuse d2g across query ranges if ws too small for 33.5MB
  // (observed ws_size ~268MB -> passes = 1)
  int passes = 1;
  while (passes < 8) {
    size_t need = 2457600 + ((size_t)N_NODES / passes) * 1024 * 4;
    if (need <= ws_size) break;
    passes <<= 1;
  }
  const int QH = N_NODES / passes;

  k_prep<<<128, 256, 0, stream>>>(x, xf, sq, deg);
  for (int p = 0; p < passes; ++p) {
    const int q00 = p * QH;
    k_dist<<<dim3(QH / 128, 8), 256, 0, stream>>>(x, sq, d2g, q00);
    k_sel <<<QH / 4, 256, 0, stream>>>(d2g, idxf, deg, q00);
  }
  k_gout<<<512, 256, 0, stream>>>(xf, idxf, deg, W0, W1, bias, out);
}